// Round 1
// baseline (461.368 us; speedup 1.0000x reference)
//
#include <hip/hip_runtime.h>

#define HW   262144      // 512*512
#define CCH  19
#define BB   8
#define NPIX 39845888ull // B*C*HW

// ---------------- Kernel A: argmax over channels + 8x8 histogram -> patches^T ----------------
// grid: B*64 blocks (one per (b, bh) 8-row strip), 512 threads.
// Output pT layout: [bc][k][l] with row stride 20 floats (k=0..255, l=0..15, pad 4).
__global__ __launch_bounds__(512) void argmax_hist_kernel(
    const float* __restrict__ x, float* __restrict__ pT)
{
    int bid = blockIdx.x;          // b*64 + bh
    int b   = bid >> 6;
    int bh  = bid & 63;
    int t   = threadIdx.x;

    __shared__ int counts[CCH * 64];
    for (int i = t; i < CCH * 64; i += 512) counts[i] = 0;
    __syncthreads();

    // strip: rows [bh*8, bh*8+8) x 512 cols, contiguous 4096 floats per channel
    const float* xb = x + (size_t)b * CCH * HW + (size_t)bh * 4096;
    #pragma unroll
    for (int it = 0; it < 2; ++it) {
        int q = it * 512 + t;                       // float4-quad index in strip [0,1024)
        const float4* xq = (const float4*)xb + q;   // channel stride = HW/4 float4s
        float4 best = xq[0];
        int bx = 0, by = 0, bz = 0, bw4 = 0;
        #pragma unroll
        for (int c = 1; c < CCH; ++c) {
            float4 v = xq[c * (HW / 4)];
            if (v.x > best.x) { best.x = v.x; bx  = c; }
            if (v.y > best.y) { best.y = v.y; by  = c; }
            if (v.z > best.z) { best.z = v.z; bz  = c; }
            if (v.w > best.w) { best.w = v.w; bw4 = c; }
        }
        int off = q * 4;                 // pixel offset in strip; 4 pixels share one 8-block
        int blk = (off & 511) >> 3;      // bw in [0,64)
        atomicAdd(&counts[bx  * 64 + blk], 1);
        atomicAdd(&counts[by  * 64 + blk], 1);
        atomicAdd(&counts[bz  * 64 + blk], 1);
        atomicAdd(&counts[bw4 * 64 + blk], 1);
    }
    __syncthreads();

    // write patches^T: l = (bh/16)*4 + bw/16 ; k = (bh%16)*16 + bw%16
    int l_hi = (bh >> 4) * 4;
    int k_hi = (bh & 15) << 4;
    for (int u = t; u < CCH * 64; u += 512) {
        int c  = u >> 6;
        int bw = u & 63;
        int l  = l_hi + (bw >> 4);
        int k  = k_hi | (bw & 15);
        pT[((size_t)(b * CCH + c) * 256 + k) * 20 + l] =
            (float)counts[u] * (1.0f / 64.0f);
    }
}

__device__ __forceinline__ float dot4(float4 a, float4 b) {
    return a.x * b.x + a.y * b.y + a.z * b.z + a.w * b.w;
}

// ---------------- Kernel C: per-tile bmm + fold + elementwise combine ----------------
// grid: B*C*32 blocks (one per (bc, mi) tile-row: 16 rows x 512 cols), 256 threads.
__global__ __launch_bounds__(256) void apply_kernel(
    const float* __restrict__ x, const float* __restrict__ att,
    const float* __restrict__ pT, float* __restrict__ out)
{
    int bid = blockIdx.x;        // bc*32 + mi
    int bc  = bid >> 5;
    int mi  = bid & 31;
    int t   = threadIdx.x;

    __shared__ __align__(16) float p_lds[256 * 20];
    const float* pb = pT + (size_t)bc * 5120;
    for (int i = t; i < 5120; i += 256) p_lds[i] = pb[i];

    // att rows for this thread's two tile-columns (mj0, mj0+16) into registers
    int mj0 = t >> 4;
    int cc  = t & 15;
    const float* ab = att + ((size_t)bc * 1024 + (size_t)mi * 32) * 16;
    const float4* a0p = (const float4*)(ab + mj0 * 16);
    const float4* a1p = (const float4*)(ab + (mj0 + 16) * 16);
    float4 a00 = a0p[0], a01 = a0p[1], a02 = a0p[2], a03 = a0p[3];
    float4 a10 = a1p[0], a11 = a1p[1], a12 = a1p[2], a13 = a1p[3];
    __syncthreads();

    size_t gb = (size_t)bc * HW + (size_t)mi * (16 * 512);
    float* out0 = out;
    float* out1 = out + NPIX;

    #pragma unroll 4
    for (int hl = 0; hl < 16; ++hl) {
        const float4* pv = (const float4*)&p_lds[(hl * 16 + cc) * 20];
        float4 p0 = pv[0], p1 = pv[1], p2 = pv[2], p3 = pv[3];
        float c0 = dot4(a00, p0) + dot4(a01, p1) + dot4(a02, p2) + dot4(a03, p3);
        float c1 = dot4(a10, p0) + dot4(a11, p1) + dot4(a12, p2) + dot4(a13, p3);
        size_t r = gb + (size_t)hl * 512;
        float x0 = x[r + t];
        float x1 = x[r + t + 256];
        float y0 = x0 + c0 * x0;
        float y1 = x1 + c1 * x1;
        out0[r + t]       = y0 + c0 * y0;
        out0[r + t + 256] = y1 + c1 * y1;
        out1[r + t]       = c0;
        out1[r + t + 256] = c1;
    }
}

extern "C" void kernel_launch(void* const* d_in, const int* in_sizes, int n_in,
                              void* d_out, int out_size, void* d_ws, size_t ws_size,
                              hipStream_t stream) {
    const float* x   = (const float*)d_in[0];
    const float* att = (const float*)d_in[1];
    float* pT  = (float*)d_ws;      // 152 * 5120 floats = ~3.1 MB
    float* out = (float*)d_out;

    argmax_hist_kernel<<<BB * 64, 512, 0, stream>>>(x, pT);
    apply_kernel<<<BB * CCH * 32, 256, 0, stream>>>(x, att, pT, out);
}